// Round 17
// baseline (74.625 us; speedup 1.0000x reference)
//
#include <hip/hip_runtime.h>
#include <hip/hip_bf16.h>

#define T_SEQ 2048
#define NH 16
#define HD 64
// 0.1 (attn scale) * log2(e) folded into q at norm time -> softmax uses exp2
#define SCALE_LOG2E 0.14426950408889634f

typedef __attribute__((ext_vector_type(8))) short bf16x8;
typedef __attribute__((ext_vector_type(4))) short bf16x4;
typedef __attribute__((ext_vector_type(4))) float f32x4;

__device__ __forceinline__ short f2bs(float f) {
  union { float f; unsigned u; } v; v.f = f;
  unsigned r = v.u + 0x7fffu + ((v.u >> 16) & 1u);
  return (short)(r >> 16);
}

__device__ __forceinline__ float bs2f(short s) {
  union { unsigned u; float f; } v;
  v.u = ((unsigned)(unsigned short)s) << 16;
  return v.f;
}

__device__ __forceinline__ unsigned cvt_pk_bf16(float lo, float hi) {
  unsigned r;
  asm("v_cvt_pk_bf16_f32 %0, %1, %2" : "=v"(r) : "v"(lo), "v"(hi));
  return r;
}

__device__ __forceinline__ void gload16(const short* g, short* l) {
  __builtin_amdgcn_global_load_lds(
      (const __attribute__((address_space(1))) void*)g,
      (__attribute__((address_space(3))) void*)l, 16, 0, 0);
}

// -------- fused prep: transpose-convert (f32 row-major -> bf16 chunk-major [128][R][8])
// + gate+rope plane (blockIdx.y==8). v1 copy rides in the proj dispatch tail.
__global__ __launch_bounds__(256) void prep(const float* __restrict__ x,
                                            const float* __restrict__ wq,
                                            const float* __restrict__ wk,
                                            const float* __restrict__ wv,
                                            const float* __restrict__ wp,
                                            const float* __restrict__ Wg,
                                            short* __restrict__ xbT,
                                            short* __restrict__ wqkvT,
                                            short* __restrict__ wpjT,
                                            float* __restrict__ gate,
                                            float2* __restrict__ rope) {
  const int rt = blockIdx.x;   // 0..95
  const int tid = threadIdx.x;
  if (blockIdx.y == 8) {       // gate + rope plane (96 blocks, grid-stride to 32768)
    for (int id = rt * 256 + tid; id < 32768; id += 96 * 256) {
      int t = id >> 4, h = id & 15;
      float acc = 0.f;
      #pragma unroll
      for (int i = 0; i < 12; ++i) acc += x[(size_t)t * 1024 + i] * Wg[h * 12 + i];
      gate[id] = 1.f / (1.f + __expf(-acc));
      #pragma unroll
      for (int j = 0; j < 2; ++j) {
        int e = id * 2 + j;
        int tt = e >> 5, p = e & 31;
        float invf = __builtin_exp2f(-0.41524101186092f * (float)p);
        float s, c;
        sincosf((float)tt * invf, &s, &c);
        rope[e] = make_float2(c, s);
      }
    }
    return;
  }
  __shared__ __attribute__((aligned(16))) short lv[64][136];
  const float* src; short* dst; int srow0, drow0, R;
  if (rt < 32)      { src = x;  dst = xbT;   R = 2048; srow0 = rt * 64;        drow0 = srow0; }
  else if (rt < 48) { src = wq; dst = wqkvT; R = 3072; srow0 = (rt - 32) * 64; drow0 = srow0; }
  else if (rt < 64) { src = wk; dst = wqkvT; R = 3072; srow0 = (rt - 48) * 64; drow0 = srow0 + 1024; }
  else if (rt < 80) { src = wv; dst = wqkvT; R = 3072; srow0 = (rt - 64) * 64; drow0 = srow0 + 2048; }
  else              { src = wp; dst = wpjT;  R = 1024; srow0 = (rt - 80) * 64; drow0 = srow0; }
  const int c0 = blockIdx.y * 16;  // chunk base (cols k = blockIdx.y*128 ..+127)
  #pragma unroll
  for (int it = 0; it < 8; ++it) {
    int e = it * 256 + tid;
    int r = e >> 5, c4 = e & 31;
    float4 v = *(const float4*)&src[(size_t)(srow0 + r) * 1024 + blockIdx.y * 128 + c4 * 4];
    bf16x4 o; o[0] = f2bs(v.x); o[1] = f2bs(v.y); o[2] = f2bs(v.z); o[3] = f2bs(v.w);
    *(bf16x4*)&lv[r][c4 * 4] = o;
  }
  __syncthreads();
  #pragma unroll
  for (int it = 0; it < 4; ++it) {  // chunk-major, row fastest -> 1KB contiguous
    int e = it * 256 + tid;
    int kc = e >> 6, r = e & 63;
    bf16x8 w = *(const bf16x8*)&lv[r][kc * 8];
    *(bf16x8*)&dst[((size_t)(c0 + kc) * R + drow0 + r) * 8] = w;
  }
}

// ---------------- GEMM: BM x BN tile, 4 waves, wave tile (BM/2)x(BN/2), BK=32,
// chunk-major operands, triple-buffer + counted vmcnt (never 0 in main loop).
// 1D grid (first ngemm blocks) with XCD-chunked bijective swizzle; blocks >= ngemm
// (proj only) do the v1 -> out-second-half f32 copy (pure-BW work overlapping GEMM).
// QKV=true (BN=128): fused epilogues -- q/k: RMSNorm+RoPE -> bf16 qb/kb;
// v: blend(v1,lamb) + permuted transpose via LDS union -> vt. QKV=false: f32 C.
template <int BM, int BN, bool QKV>
__global__ __launch_bounds__(256) void gemm(const short* __restrict__ A,
                                            const short* __restrict__ B,
                                            float* __restrict__ C,
                                            short* __restrict__ qb,
                                            short* __restrict__ kb,
                                            short* __restrict__ vt,
                                            const float* __restrict__ v1,
                                            const float* __restrict__ lambp,
                                            const float2* __restrict__ rope,
                                            int M, int N, int K, int ngemm) {
  constexpr int MF = BM / 32, NB = BN / 32;   // fragments per wave
  constexpr int LA = BM / 64, LB = BN / 64;   // gload16 per wave per step
  if constexpr (!QKV) {
    if ((int)blockIdx.x >= ngemm) {  // v1 -> out[T*1024..] copy (8 rows per block)
      const int cb = blockIdx.x - ngemm;
      const float* s = v1 + (size_t)cb * 8192;
      float* d = C + (size_t)T_SEQ * 1024 + (size_t)cb * 8192;
      #pragma unroll
      for (int it = 0; it < 8; ++it) {
        int e = it * 256 + threadIdx.x;
        *(float4*)&d[e * 4] = *(const float4*)&s[e * 4];
      }
      return;
    }
  }
  __shared__ union {
    struct { short As[3][4][BM][8]; short Bs[3][4][BN][8]; } g;
    short lv[BM][130];            // v-transpose tile (QKV only)
  } sm;
  const int tid = threadIdx.x;
  const int lane = tid & 63, wid = tid >> 6;
  const int lr = lane & 15, lg = lane >> 4;
  const int wm = (wid >> 1) * (BM / 2), wn = (wid & 1) * (BN / 2);
  // XCD-chunked swizzle: bid%8 = XCD; each XCD gets a contiguous by-major range
  const int nper = ngemm >> 3;
  const int tile = (blockIdx.x & 7) * nper + (blockIdx.x >> 3);
  const int gx = M / BM;
  const int bm = (tile % gx) * BM, bn = (tile / gx) * BN;
  const short* Ap = A + ((size_t)wid * M + bm + lane) * 8;
  const short* Bp = B + ((size_t)wid * N + bn + lane) * 8;
  f32x4 acc[MF][NB] = {};
  auto stage = [&](int buf, int k0) {
    #pragma unroll
    for (int g = 0; g < LA; ++g)
      gload16(Ap + (size_t)k0 * M + g * 512, &sm.g.As[buf][wid][64 * g][0]);
    #pragma unroll
    for (int g = 0; g < LB; ++g)
      gload16(Bp + (size_t)k0 * N + g * 512, &sm.g.Bs[buf][wid][64 * g][0]);
  };
  auto compute = [&](int buf) {
    bf16x8 af[MF], bfr[NB];
    #pragma unroll
    for (int m = 0; m < MF; ++m) af[m] = *(const bf16x8*)&sm.g.As[buf][lg][wm + m * 16 + lr][0];
    #pragma unroll
    for (int n = 0; n < NB; ++n) bfr[n] = *(const bf16x8*)&sm.g.Bs[buf][lg][wn + n * 16 + lr][0];
    #pragma unroll
    for (int m = 0; m < MF; ++m)
      #pragma unroll
      for (int n = 0; n < NB; ++n)
        acc[m][n] = __builtin_amdgcn_mfma_f32_16x16x32_bf16(af[m], bfr[n], acc[m][n], 0, 0, 0);
  };
  const int nsteps = K >> 5;
  stage(0, 0);
  stage(1, 32);
  int cur = 0;
  for (int ks = 0; ks < nsteps - 1; ++ks) {
    // wait only the oldest stage (LA+LB loads); next stage stays in flight
    if constexpr (LA + LB == 4)      asm volatile("s_waitcnt vmcnt(4)" ::: "memory");
    else if constexpr (LA + LB == 3) asm volatile("s_waitcnt vmcnt(3)" ::: "memory");
    else                             asm volatile("s_waitcnt vmcnt(2)" ::: "memory");
    __builtin_amdgcn_s_barrier();
    __builtin_amdgcn_sched_barrier(0);
    int s2 = cur + 2; if (s2 >= 3) s2 -= 3;
    if (ks + 2 < nsteps) stage(s2, (ks + 2) * 32);
    compute(cur);
    cur = (cur == 2) ? 0 : cur + 1;
  }
  asm volatile("s_waitcnt vmcnt(0)" ::: "memory");
  __builtin_amdgcn_s_barrier();
  __builtin_amdgcn_sched_barrier(0);
  compute(cur);

  if constexpr (QKV) {
    if (bn < 2048) {  // q or k: wave cols = exactly one head (BN=128, NB=4)
      const bool isq = (bn < 1024);
      short* dst = isq ? qb : kb;
      const int h = ((bn + wn) & 1023) >> 6;
      #pragma unroll
      for (int m = 0; m < MF; ++m)
        #pragma unroll
        for (int r = 0; r < 4; ++r) {
          const int t = bm + wm + m * 16 + 4 * lg + r;
          float ss = acc[m][0][r] * acc[m][0][r] + acc[m][1][r] * acc[m][1][r]
                   + acc[m][2][r] * acc[m][2][r] + acc[m][3][r] * acc[m][3][r];
          ss += __shfl_xor(ss, 1);
          ss += __shfl_xor(ss, 2);
          ss += __shfl_xor(ss, 4);
          ss += __shfl_xor(ss, 8);
          const float rms = rsqrtf(ss * (1.f / 64.f) + 1e-6f);
          short* row = dst + ((size_t)h * T_SEQ + t) * 64;
          #pragma unroll
          for (int n2 = 0; n2 < 2; ++n2) {  // rope pair (d, d+32) = frags (n2, n2+2)
            float x1 = acc[m][n2][r] * rms, x2 = acc[m][n2 + 2][r] * rms;
            float2 cs = rope[t * 32 + n2 * 16 + lr];
            float y1 = x1 * cs.x + x2 * cs.y;
            float y2 = x2 * cs.x - x1 * cs.y;
            if (isq) { y1 *= SCALE_LOG2E; y2 *= SCALE_LOG2E; }
            row[n2 * 16 + lr] = f2bs(y1);
            row[32 + n2 * 16 + lr] = f2bs(y2);
          }
        }
    } else {  // v: blend with v1, permuted transpose via LDS, write vt[h][d][t']
      const float Lb = *lambp;
      const int h0 = (bn - 2048) >> 6;  // block covers heads h0, h0+1
      __syncthreads();                  // all waves done reading As/Bs (union!)
      #pragma unroll
      for (int m = 0; m < MF; ++m)
        #pragma unroll
        for (int r = 0; r < 4; ++r) {
          const int tl = wm + m * 16 + 4 * lg + r;
          const size_t vrow = (size_t)(bm + tl) * 1024 + h0 * 64;
          #pragma unroll
          for (int n = 0; n < NB; ++n) {
            const int col = wn + n * 16 + lr;
            float w = v1[vrow + col];
            sm.lv[tl][col] = f2bs((1.f - Lb) * acc[m][n][r] + Lb * w);
          }
        }
      __syncthreads();
      // position c in each 32-block holds actual t-row (c&96)|((c&1)<<4)|((c>>1)&15)
      constexpr int TPB = BM / 8;       // bf16x8 chunks per (hh,d) row
      #pragma unroll
      for (int it = 0; it < BM / 16; ++it) {
        int u = it * 256 + tid;         // u in [0, 16*BM)
        int c0 = (u % TPB) * 8;
        int d = (u / TPB) & 63;
        int hh = u / (TPB * 64);
        bf16x8 w;
        #pragma unroll
        for (int j = 0; j < 8; ++j) {
          int c = c0 + j;
          int src = (c & 96) | ((c & 1) << 4) | ((c >> 1) & 15);
          w[j] = sm.lv[src][hh * 64 + d];
        }
        *(bf16x8*)&vt[((size_t)(h0 + hh) * 64 + d) * T_SEQ + bm + c0] = w;
      }
    }
  } else {
    #pragma unroll
    for (int m = 0; m < MF; ++m)
      #pragma unroll
      for (int r = 0; r < 4; ++r) {
        const int t = bm + wm + m * 16 + 4 * lg + r;
        float* Cr = C + (size_t)t * N + bn + wn + lr;
        #pragma unroll
        for (int n = 0; n < NB; ++n) Cr[n * 16] = acc[m][n][r];
      }
  }
}

// ---------------- causal attention, split-KV ----------------
// 1280 near-uniform blocks (~5/CU): latency chains hidden by TLP. Partials: bf16 O +
// f32 lsum, compact slot = head*80 + b. Cross-XCD visibility of partials comes from
// the DISPATCH BOUNDARY (round-15 lesson: per-block device-scope fences force L2
// writebacks on non-coherent XCD L2s -> 3.3x slowdown). ns==1 groups (qg<8, strip 0
// only) skip partials entirely: gate+normalize in-register and write obT directly.
__global__ __launch_bounds__(256) void attn(const short* __restrict__ qb,
                                            const short* __restrict__ kb,
                                            const short* __restrict__ vtp,
                                            short* __restrict__ partO,
                                            float* __restrict__ partL,
                                            const float* __restrict__ gate,
                                            short* __restrict__ obT) {
  __shared__ __attribute__((aligned(16))) short Ks[2][4096];
  __shared__ __attribute__((aligned(16))) short Vs[2][4096];
  __shared__ __attribute__((aligned(16))) short p_lds[4][16][72];
  const int head = blockIdx.x & 15;
  const int b = blockIdx.x >> 4;  // 0..79
  int strip, qg;  // heavy-first within each strip class
  if (b < 32)      { strip = 0; qg = 31 - b; }
  else if (b < 56) { strip = 1; qg = 63 - b; }
  else if (b < 72) { strip = 2; qg = 87 - b; }
  else             { strip = 3; qg = 103 - b; }
  const int nt = min(8, qg + 1 - strip * 8);
  const int lane = threadIdx.x & 63, wid = threadIdx.x >> 6;
  const int lr = lane & 15, lg = lane >> 4;
  const int qt0 = qg * 64 + wid * 16;
  const short* Q = qb + (size_t)head * (T_SEQ * HD);
  const short* Kp = kb + (size_t)head * (T_SEQ * HD);
  const short* Vt = vtp + (size_t)head * (HD * T_SEQ);
  short (*P)[72] = p_lds[wid];

  bf16x8 aq0 = *(const bf16x8*)&Q[(size_t)(qt0 + lr) * HD + 8 * lg];
  bf16x8 aq1 = *(const bf16x8*)&Q[(size_t)(qt0 + lr) * HD + 32 + 8 * lg];
  f32x4 accO[4] = {};
  float lsum[4] = {0.f, 0.f, 0.f, 0.f};

  auto stage = [&](int buf, int jg) {
    const int kv0 = jg * 64;
    #pragma unroll
    for (int i = 0; i < 2; ++i) {
      int s = i * 256 + wid * 64 + lane;
      int row = s >> 3;
      int cG = (s & 7) ^ (row & 7);  // inverse-swizzled source chunk
      gload16(Kp + (size_t)(kv0 + row) * HD + cG * 8,
              &Ks[buf][(size_t)(i * 256 + wid * 64) * 8]);
      gload16(Vt + (size_t)row * T_SEQ + kv0 + cG * 8,
              &Vs[buf][(size_t)(i * 256 + wid * 64) * 8]);
    }
  };
  stage(0, strip * 8);
  for (int j = 0; j < nt; ++j) {
    const int jg = strip * 8 + j;
    __syncthreads();
    if (j + 1 < nt) stage((j + 1) & 1, jg + 1);
    const short* Kb = Ks[j & 1];
    const short* Vb = Vs[j & 1];
    f32x4 st[4];
    #pragma unroll
    for (int t = 0; t < 4; ++t) {
      int row = 16 * t + lr;
      int c0 = lg ^ (row & 7);
      bf16x8 k0 = *(const bf16x8*)&Kb[row * 64 + c0 * 8];
      bf16x8 k1 = *(const bf16x8*)&Kb[row * 64 + (c0 ^ 4) * 8];
      f32x4 s = {};
      s = __builtin_amdgcn_mfma_f32_16x16x32_bf16(aq0, k0, s, 0, 0, 0);
      s = __builtin_amdgcn_mfma_f32_16x16x32_bf16(aq1, k1, s, 0, 0, 0);
      st[t] = s;
    }
    if (jg == qg) {
      #pragma unroll
      for (int t = 0; t < 4; ++t)
        #pragma unroll
        for (int r = 0; r < 4; ++r)
          st[t][r] = (16 * t + lr > wid * 16 + 4 * lg + r) ? -1e30f : st[t][r];
    }
    #pragma unroll
    for (int r = 0; r < 4; ++r) {
      float p0 = __builtin_exp2f(st[0][r]);
      float p1 = __builtin_exp2f(st[1][r]);
      float p2 = __builtin_exp2f(st[2][r]);
      float p3 = __builtin_exp2f(st[3][r]);
      lsum[r] += (p0 + p1) + (p2 + p3);
      *(unsigned*)&P[4 * lg + r][2 * lr] = cvt_pk_bf16(p0, p1);
      *(unsigned*)&P[4 * lg + r][32 + 2 * lr] = cvt_pk_bf16(p2, p3);
    }
    asm volatile("s_waitcnt lgkmcnt(0)" ::: "memory");
    __builtin_amdgcn_sched_barrier(0);
    bf16x8 pa0 = *(const bf16x8*)&P[lr][8 * lg];
    bf16x8 pa1 = *(const bf16x8*)&P[lr][32 + 8 * lg];
    #pragma unroll
    for (int nv = 0; nv < 4; ++nv) {
      int row0 = nv * 16 + lr;
      int c0 = lg ^ (row0 & 7);
      bf16x8 v0 = *(const bf16x8*)&Vb[row0 * 64 + c0 * 8];
      bf16x8 v1e = *(const bf16x8*)&Vb[row0 * 64 + (c0 ^ 4) * 8];
      accO[nv] = __builtin_amdgcn_mfma_f32_16x16x32_bf16(pa0, v0, accO[nv], 0, 0, 0);
      accO[nv] = __builtin_amdgcn_mfma_f32_16x16x32_bf16(pa1, v1e, accO[nv], 0, 0, 0);
    }
  }

  if (qg < 8) {  // ns==1: this block is the only contributor -> write obT directly
    #pragma unroll
    for (int r = 0; r < 4; ++r) {
      float sres = lsum[r];
      sres += __shfl_xor(sres, 1);
      sres += __shfl_xor(sres, 2);
      sres += __shfl_xor(sres, 4);
      sres += __shfl_xor(sres, 8);
      const int t = qt0 + 4 * lg + r;
      const float gs = gate[t * 16 + head] / sres;
      #pragma unroll
      for (int nv = 0; nv < 4; ++nv) {
        const int col = nv * 16 + lr;
        obT[((size_t)(head * 8 + (col >> 3)) * T_SEQ + t) * 8 + (col & 7)] =
            f2bs(accO[nv][r] * gs);
      }
    }
    return;
  }
  short* pO = partO + (size_t)(head * 80 + b) * 4096;
  float* pL = partL + (size_t)(head * 80 + b) * 64;
  #pragma unroll
  for (int r = 0; r < 4; ++r) {
    float sres = lsum[r];
    sres += __shfl_xor(sres, 1);
    sres += __shfl_xor(sres, 2);
    sres += __shfl_xor(sres, 4);
    sres += __shfl_xor(sres, 8);
    int row = wid * 16 + 4 * lg + r;
    #pragma unroll
    for (int nv = 0; nv < 4; ++nv)
      pO[row * 64 + nv * 16 + lr] = f2bs(accO[nv][r]);
    if (lr == 0) pL[row] = sres;
  }
}

// ------- combine split-KV partials (qg>=8 only), apply gate, write chunk-major obT
__global__ __launch_bounds__(256) void attn_reduce(const short* __restrict__ partO,
                                                   const float* __restrict__ partL,
                                                   const float* __restrict__ gate,
                                                   short* __restrict__ obT) {
  const int head = blockIdx.x & 15;
  const int qg = 8 + (blockIdx.x >> 4);  // 8..31
  const int ns = (qg >> 3) + 1;
  const int tid = threadIdx.x;
  const int row = tid >> 2, q4 = tid & 3;
  const int sbase[4] = {0, 32, 56, 72};  // strip -> b base (b = sbase[s] + 31 - qg)
  f32x4 o[4] = {};
  float l = 0.f;
  for (int s = 0; s < ns; ++s) {
    const int slot = head * 80 + sbase[s] + 31 - qg;
    const short* pb = partO + (size_t)slot * 4096;
    #pragma unroll
    for (int c = 0; c < 4; ++c) {
      bf16x4 v = *(const bf16x4*)&pb[row * 64 + q4 * 16 + c * 4];
      #pragma unroll
      for (int j = 0; j < 4; ++j) o[c][j] += bs2f(v[j]);
    }
    l += partL[(size_t)slot * 64 + row];
  }
  const int t = qg * 64 + row;
  const float gs = gate[t * 16 + head] / l;
  const int cg0 = head * 8 + q4 * 2;
  bf16x8 w0, w1;
  #pragma unroll
  for (int j = 0; j < 4; ++j) {
    w0[j]     = f2bs(o[0][j] * gs);
    w0[4 + j] = f2bs(o[1][j] * gs);
    w1[j]     = f2bs(o[2][j] * gs);
    w1[4 + j] = f2bs(o[3][j] * gs);
  }
  *(bf16x8*)&obT[((size_t)cg0 * 2048 + t) * 8] = w0;
  *(bf16x8*)&obT[((size_t)(cg0 + 1) * 2048 + t) * 8] = w1;
}

extern "C" void kernel_launch(void* const* d_in, const int* in_sizes, int n_in,
                              void* d_out, int out_size, void* d_ws, size_t ws_size,
                              hipStream_t stream) {
  const float* x     = (const float*)d_in[0];
  const float* v1    = (const float*)d_in[1];
  const float* Wq    = (const float*)d_in[2];
  const float* Wk    = (const float*)d_in[3];
  const float* Wv    = (const float*)d_in[4];
  const float* Wproj = (const float*)d_in[5];
  const float* lamb  = (const float*)d_in[6];
  const float* Wgate = (const float*)d_in[7];
  float* out = (float*)d_out;

  char* ws = (char*)d_ws;
  short*  xbT   = (short*)(ws);                       // 4MB chunk-major x (alias obT)
  short*  wqkvT = (short*)(ws + ((size_t)4  << 20));  // 6MB chunk-major Wq|Wk|Wv
  short*  wpjT  = (short*)(ws + ((size_t)10 << 20));  // 2MB chunk-major Wproj
  short*  partO = (short*)(ws + ((size_t)12 << 20));  // 10.5MB bf16 O partials
  float*  partL = (float*)(ws + ((size_t)23 << 20));  // 327KB f32 lsum partials
  float2* rope  = (float2*)(ws + ((size_t)34 << 20)); // 512KB
  short*  qb    = (short*)(ws + ((size_t)36 << 20));  // 4MB
  short*  kb    = (short*)(ws + ((size_t)40 << 20));  // 4MB
  short*  vt    = (short*)(ws + ((size_t)44 << 20));  // 4MB
  float*  gate  = (float*)(ws + ((size_t)48 << 20));  // 128KB
  short*  obT   = xbT;  // xbT dead after QKV GEMM

  prep<<<dim3(96, 9), 256, 0, stream>>>(x, Wq, Wk, Wv, Wproj, Wgate,
                                        xbT, wqkvT, wpjT, gate, rope);
  // QKV: 768 blocks = exactly 3/CU uniform (36KB LDS), XCD-chunked (96 tiles/XCD)
  gemm<64, 128, true><<<768, 256, 0, stream>>>(xbT, wqkvT, nullptr, qb, kb, vt,
                                               v1, lamb, rope, 2048, 3072, 1024, 768);
  attn<<<1280, 256, 0, stream>>>(qb, kb, vt, partO, partL, gate, obT);
  attn_reduce<<<384, 256, 0, stream>>>(partO, partL, gate, obT);
  // proj: 256 GEMM blocks (BN=128: 8 MFMA/step, 1/CU uniform) + 256 v1-copy tail
  gemm<64, 128, false><<<512, 256, 0, stream>>>(obT, wpjT, out, nullptr, nullptr,
                                                nullptr, v1, nullptr, nullptr,
                                                2048, 1024, 1024, 256);
}

// Round 18
// 71.780 us; speedup vs baseline: 1.0396x; 1.0396x over previous
//
#include <hip/hip_runtime.h>
#include <hip/hip_bf16.h>

#define T_SEQ 2048
#define NH 16
#define HD 64
// 0.1 (attn scale) * log2(e) folded into q at norm time -> softmax uses exp2
#define SCALE_LOG2E 0.14426950408889634f

typedef __attribute__((ext_vector_type(8))) short bf16x8;
typedef __attribute__((ext_vector_type(4))) short bf16x4;
typedef __attribute__((ext_vector_type(4))) float f32x4;

__device__ __forceinline__ short f2bs(float f) {
  union { float f; unsigned u; } v; v.f = f;
  unsigned r = v.u + 0x7fffu + ((v.u >> 16) & 1u);
  return (short)(r >> 16);
}

__device__ __forceinline__ float bs2f(short s) {
  union { unsigned u; float f; } v;
  v.u = ((unsigned)(unsigned short)s) << 16;
  return v.f;
}

__device__ __forceinline__ unsigned cvt_pk_bf16(float lo, float hi) {
  unsigned r;
  asm("v_cvt_pk_bf16_f32 %0, %1, %2" : "=v"(r) : "v"(lo), "v"(hi));
  return r;
}

__device__ __forceinline__ void gload16(const short* g, short* l) {
  __builtin_amdgcn_global_load_lds(
      (const __attribute__((address_space(1))) void*)g,
      (__attribute__((address_space(3))) void*)l, 16, 0, 0);
}

// -------- fused prep: transpose-convert (f32 row-major -> bf16 chunk-major [128][R][8])
// + gate+rope plane (blockIdx.y==8). v1 copy rides in the proj dispatch tail.
__global__ __launch_bounds__(256) void prep(const float* __restrict__ x,
                                            const float* __restrict__ wq,
                                            const float* __restrict__ wk,
                                            const float* __restrict__ wv,
                                            const float* __restrict__ wp,
                                            const float* __restrict__ Wg,
                                            short* __restrict__ xbT,
                                            short* __restrict__ wqkvT,
                                            short* __restrict__ wpjT,
                                            float* __restrict__ gate,
                                            float2* __restrict__ rope) {
  const int rt = blockIdx.x;   // 0..95
  const int tid = threadIdx.x;
  if (blockIdx.y == 8) {       // gate + rope plane (96 blocks, grid-stride to 32768)
    for (int id = rt * 256 + tid; id < 32768; id += 96 * 256) {
      int t = id >> 4, h = id & 15;
      float acc = 0.f;
      #pragma unroll
      for (int i = 0; i < 12; ++i) acc += x[(size_t)t * 1024 + i] * Wg[h * 12 + i];
      gate[id] = 1.f / (1.f + __expf(-acc));
      #pragma unroll
      for (int j = 0; j < 2; ++j) {
        int e = id * 2 + j;
        int tt = e >> 5, p = e & 31;
        float invf = __builtin_exp2f(-0.41524101186092f * (float)p);
        float s, c;
        sincosf((float)tt * invf, &s, &c);
        rope[e] = make_float2(c, s);
      }
    }
    return;
  }
  __shared__ __attribute__((aligned(16))) short lv[64][136];
  const float* src; short* dst; int srow0, drow0, R;
  if (rt < 32)      { src = x;  dst = xbT;   R = 2048; srow0 = rt * 64;        drow0 = srow0; }
  else if (rt < 48) { src = wq; dst = wqkvT; R = 3072; srow0 = (rt - 32) * 64; drow0 = srow0; }
  else if (rt < 64) { src = wk; dst = wqkvT; R = 3072; srow0 = (rt - 48) * 64; drow0 = srow0 + 1024; }
  else if (rt < 80) { src = wv; dst = wqkvT; R = 3072; srow0 = (rt - 64) * 64; drow0 = srow0 + 2048; }
  else              { src = wp; dst = wpjT;  R = 1024; srow0 = (rt - 80) * 64; drow0 = srow0; }
  const int c0 = blockIdx.y * 16;  // chunk base (cols k = blockIdx.y*128 ..+127)
  #pragma unroll
  for (int it = 0; it < 8; ++it) {
    int e = it * 256 + tid;
    int r = e >> 5, c4 = e & 31;
    float4 v = *(const float4*)&src[(size_t)(srow0 + r) * 1024 + blockIdx.y * 128 + c4 * 4];
    bf16x4 o; o[0] = f2bs(v.x); o[1] = f2bs(v.y); o[2] = f2bs(v.z); o[3] = f2bs(v.w);
    *(bf16x4*)&lv[r][c4 * 4] = o;
  }
  __syncthreads();
  #pragma unroll
  for (int it = 0; it < 4; ++it) {  // chunk-major, row fastest -> 1KB contiguous
    int e = it * 256 + tid;
    int kc = e >> 6, r = e & 63;
    bf16x8 w = *(const bf16x8*)&lv[r][kc * 8];
    *(bf16x8*)&dst[((size_t)(c0 + kc) * R + drow0 + r) * 8] = w;
  }
}

// ---------------- GEMM: BM x BN tile, 4 waves, wave tile (BM/2)x(BN/2), BK=32,
// chunk-major operands, triple-buffer + counted vmcnt (never 0 in main loop).
// 1D grid (first ngemm blocks) with XCD-chunked bijective swizzle; blocks >= ngemm
// (proj only) do the v1 -> out-second-half f32 copy (pure-BW work overlapping GEMM).
// QKV=true (BN=128): fused epilogues -- q/k: RMSNorm+RoPE -> bf16 qb/kb;
// v: blend(v1,lamb) + permuted transpose via LDS union -> vt. QKV=false: f32 C.
template <int BM, int BN, bool QKV>
__global__ __launch_bounds__(256) void gemm(const short* __restrict__ A,
                                            const short* __restrict__ B,
                                            float* __restrict__ C,
                                            short* __restrict__ qb,
                                            short* __restrict__ kb,
                                            short* __restrict__ vt,
                                            const float* __restrict__ v1,
                                            const float* __restrict__ lambp,
                                            const float2* __restrict__ rope,
                                            int M, int N, int K, int ngemm) {
  constexpr int MF = BM / 32, NB = BN / 32;   // fragments per wave
  constexpr int LA = BM / 64, LB = BN / 64;   // gload16 per wave per step
  if constexpr (!QKV) {
    if ((int)blockIdx.x >= ngemm) {  // v1 -> out[T*1024..] copy (8 rows per block)
      const int cb = blockIdx.x - ngemm;
      const float* s = v1 + (size_t)cb * 8192;
      float* d = C + (size_t)T_SEQ * 1024 + (size_t)cb * 8192;
      #pragma unroll
      for (int it = 0; it < 8; ++it) {
        int e = it * 256 + threadIdx.x;
        *(float4*)&d[e * 4] = *(const float4*)&s[e * 4];
      }
      return;
    }
  }
  __shared__ union {
    struct { short As[3][4][BM][8]; short Bs[3][4][BN][8]; } g;
    short lv[BM][130];            // v-transpose tile (QKV only)
  } sm;
  const int tid = threadIdx.x;
  const int lane = tid & 63, wid = tid >> 6;
  const int lr = lane & 15, lg = lane >> 4;
  const int wm = (wid >> 1) * (BM / 2), wn = (wid & 1) * (BN / 2);
  // XCD-chunked swizzle: bid%8 = XCD; each XCD gets a contiguous by-major range
  const int nper = ngemm >> 3;
  const int tile = (blockIdx.x & 7) * nper + (blockIdx.x >> 3);
  const int gx = M / BM;
  const int bm = (tile % gx) * BM, bn = (tile / gx) * BN;
  const short* Ap = A + ((size_t)wid * M + bm + lane) * 8;
  const short* Bp = B + ((size_t)wid * N + bn + lane) * 8;
  f32x4 acc[MF][NB] = {};
  auto stage = [&](int buf, int k0) {
    #pragma unroll
    for (int g = 0; g < LA; ++g)
      gload16(Ap + (size_t)k0 * M + g * 512, &sm.g.As[buf][wid][64 * g][0]);
    #pragma unroll
    for (int g = 0; g < LB; ++g)
      gload16(Bp + (size_t)k0 * N + g * 512, &sm.g.Bs[buf][wid][64 * g][0]);
  };
  auto compute = [&](int buf) {
    bf16x8 af[MF], bfr[NB];
    #pragma unroll
    for (int m = 0; m < MF; ++m) af[m] = *(const bf16x8*)&sm.g.As[buf][lg][wm + m * 16 + lr][0];
    #pragma unroll
    for (int n = 0; n < NB; ++n) bfr[n] = *(const bf16x8*)&sm.g.Bs[buf][lg][wn + n * 16 + lr][0];
    #pragma unroll
    for (int m = 0; m < MF; ++m)
      #pragma unroll
      for (int n = 0; n < NB; ++n)
        acc[m][n] = __builtin_amdgcn_mfma_f32_16x16x32_bf16(af[m], bfr[n], acc[m][n], 0, 0, 0);
  };
  const int nsteps = K >> 5;
  stage(0, 0);
  stage(1, 32);
  int cur = 0;
  for (int ks = 0; ks < nsteps - 1; ++ks) {
    // wait only the oldest stage (LA+LB loads); next stage stays in flight
    if constexpr (LA + LB == 4)      asm volatile("s_waitcnt vmcnt(4)" ::: "memory");
    else if constexpr (LA + LB == 3) asm volatile("s_waitcnt vmcnt(3)" ::: "memory");
    else                             asm volatile("s_waitcnt vmcnt(2)" ::: "memory");
    __builtin_amdgcn_s_barrier();
    __builtin_amdgcn_sched_barrier(0);
    int s2 = cur + 2; if (s2 >= 3) s2 -= 3;
    if (ks + 2 < nsteps) stage(s2, (ks + 2) * 32);
    compute(cur);
    cur = (cur == 2) ? 0 : cur + 1;
  }
  asm volatile("s_waitcnt vmcnt(0)" ::: "memory");
  __builtin_amdgcn_s_barrier();
  __builtin_amdgcn_sched_barrier(0);
  compute(cur);

  if constexpr (QKV) {
    if (bn < 2048) {  // q or k: wave cols = exactly one head (BN=128, NB=4)
      const bool isq = (bn < 1024);
      short* dst = isq ? qb : kb;
      const int h = ((bn + wn) & 1023) >> 6;
      #pragma unroll
      for (int m = 0; m < MF; ++m)
        #pragma unroll
        for (int r = 0; r < 4; ++r) {
          const int t = bm + wm + m * 16 + 4 * lg + r;
          float ss = acc[m][0][r] * acc[m][0][r] + acc[m][1][r] * acc[m][1][r]
                   + acc[m][2][r] * acc[m][2][r] + acc[m][3][r] * acc[m][3][r];
          ss += __shfl_xor(ss, 1);
          ss += __shfl_xor(ss, 2);
          ss += __shfl_xor(ss, 4);
          ss += __shfl_xor(ss, 8);
          const float rms = rsqrtf(ss * (1.f / 64.f) + 1e-6f);
          short* row = dst + ((size_t)h * T_SEQ + t) * 64;
          #pragma unroll
          for (int n2 = 0; n2 < 2; ++n2) {  // rope pair (d, d+32) = frags (n2, n2+2)
            float x1 = acc[m][n2][r] * rms, x2 = acc[m][n2 + 2][r] * rms;
            float2 cs = rope[t * 32 + n2 * 16 + lr];
            float y1 = x1 * cs.x + x2 * cs.y;
            float y2 = x2 * cs.x - x1 * cs.y;
            if (isq) { y1 *= SCALE_LOG2E; y2 *= SCALE_LOG2E; }
            row[n2 * 16 + lr] = f2bs(y1);
            row[32 + n2 * 16 + lr] = f2bs(y2);
          }
        }
    } else {  // v: blend with v1, permuted transpose via LDS, write vt[h][d][t']
      const float Lb = *lambp;
      const int h0 = (bn - 2048) >> 6;  // block covers heads h0, h0+1
      __syncthreads();                  // all waves done reading As/Bs (union!)
      #pragma unroll
      for (int m = 0; m < MF; ++m)
        #pragma unroll
        for (int r = 0; r < 4; ++r) {
          const int tl = wm + m * 16 + 4 * lg + r;
          const size_t vrow = (size_t)(bm + tl) * 1024 + h0 * 64;
          #pragma unroll
          for (int n = 0; n < NB; ++n) {
            const int col = wn + n * 16 + lr;
            float w = v1[vrow + col];
            sm.lv[tl][col] = f2bs((1.f - Lb) * acc[m][n][r] + Lb * w);
          }
        }
      __syncthreads();
      // position c in each 32-block holds actual t-row (c&96)|((c&1)<<4)|((c>>1)&15)
      constexpr int TPB = BM / 8;       // bf16x8 chunks per (hh,d) row
      #pragma unroll
      for (int it = 0; it < BM / 16; ++it) {
        int u = it * 256 + tid;         // u in [0, 16*BM)
        int c0 = (u % TPB) * 8;
        int d = (u / TPB) & 63;
        int hh = u / (TPB * 64);
        bf16x8 w;
        #pragma unroll
        for (int j = 0; j < 8; ++j) {
          int c = c0 + j;
          int src = (c & 96) | ((c & 1) << 4) | ((c >> 1) & 15);
          w[j] = sm.lv[src][hh * 64 + d];
        }
        *(bf16x8*)&vt[((size_t)(h0 + hh) * 64 + d) * T_SEQ + bm + c0] = w;
      }
    }
  } else {
    #pragma unroll
    for (int m = 0; m < MF; ++m)
      #pragma unroll
      for (int r = 0; r < 4; ++r) {
        const int t = bm + wm + m * 16 + 4 * lg + r;
        float* Cr = C + (size_t)t * N + bn + wn + lr;
        #pragma unroll
        for (int n = 0; n < NB; ++n) Cr[n * 16] = acc[m][n][r];
      }
  }
}

// ---------------- causal attention, split-KV ----------------
// 1280 near-uniform blocks. V is SINGLE-buffered (8KB saved): staged at iteration
// top (not needed until after QK+softmax ~400cy later), guarded by counted
// s_waitcnt vmcnt(2) before PV (waits only the 2 oldest = V loads; next K tile's
// loads stay in flight). LDS 42 -> 33.8KB => 4 blocks/CU (16 waves/CU, +33% TLP)
// for this latency-bound kernel. Partials: bf16 O + f32 lsum; cross-XCD visibility
// via the dispatch boundary (round-15 lesson: in-kernel fences -> 3.3x slowdown).
// ns==1 groups (qg<8) write gated obT directly, skipping partials.
__global__ __launch_bounds__(256) void attn(const short* __restrict__ qb,
                                            const short* __restrict__ kb,
                                            const short* __restrict__ vtp,
                                            short* __restrict__ partO,
                                            float* __restrict__ partL,
                                            const float* __restrict__ gate,
                                            short* __restrict__ obT) {
  __shared__ __attribute__((aligned(16))) short Ks[2][4096];
  __shared__ __attribute__((aligned(16))) short Vs[4096];
  __shared__ __attribute__((aligned(16))) short p_lds[4][16][72];
  const int head = blockIdx.x & 15;
  const int b = blockIdx.x >> 4;  // 0..79
  int strip, qg;  // heavy-first within each strip class
  if (b < 32)      { strip = 0; qg = 31 - b; }
  else if (b < 56) { strip = 1; qg = 63 - b; }
  else if (b < 72) { strip = 2; qg = 87 - b; }
  else             { strip = 3; qg = 103 - b; }
  const int nt = min(8, qg + 1 - strip * 8);
  const int lane = threadIdx.x & 63, wid = threadIdx.x >> 6;
  const int lr = lane & 15, lg = lane >> 4;
  const int qt0 = qg * 64 + wid * 16;
  const short* Q = qb + (size_t)head * (T_SEQ * HD);
  const short* Kp = kb + (size_t)head * (T_SEQ * HD);
  const short* Vt = vtp + (size_t)head * (HD * T_SEQ);
  short (*P)[72] = p_lds[wid];

  bf16x8 aq0 = *(const bf16x8*)&Q[(size_t)(qt0 + lr) * HD + 8 * lg];
  bf16x8 aq1 = *(const bf16x8*)&Q[(size_t)(qt0 + lr) * HD + 32 + 8 * lg];
  f32x4 accO[4] = {};
  float lsum[4] = {0.f, 0.f, 0.f, 0.f};

  auto stageK = [&](int buf, int jg) {
    const int kv0 = jg * 64;
    #pragma unroll
    for (int i = 0; i < 2; ++i) {
      int s = i * 256 + wid * 64 + lane;
      int row = s >> 3;
      int cG = (s & 7) ^ (row & 7);  // inverse-swizzled source chunk
      gload16(Kp + (size_t)(kv0 + row) * HD + cG * 8,
              &Ks[buf][(size_t)(i * 256 + wid * 64) * 8]);
    }
  };
  auto stageV = [&](int jg) {
    const int kv0 = jg * 64;
    #pragma unroll
    for (int i = 0; i < 2; ++i) {
      int s = i * 256 + wid * 64 + lane;
      int row = s >> 3;
      int cG = (s & 7) ^ (row & 7);
      gload16(Vt + (size_t)row * T_SEQ + kv0 + cG * 8,
              &Vs[(size_t)(i * 256 + wid * 64) * 8]);
    }
  };
  stageK(0, strip * 8);
  for (int j = 0; j < nt; ++j) {
    const int jg = strip * 8 + j;
    __syncthreads();       // drains K(j) arrival AND all waves' PV reads of Vs(j-1)
    stageV(jg);            // 2 loads (oldest in queue) — land during QK+softmax
    if (j + 1 < nt) stageK((j + 1) & 1, jg + 1);  // 2 more, stay in flight past PV
    const short* Kb = Ks[j & 1];
    f32x4 st[4];
    #pragma unroll
    for (int t = 0; t < 4; ++t) {
      int row = 16 * t + lr;
      int c0 = lg ^ (row & 7);
      bf16x8 k0 = *(const bf16x8*)&Kb[row * 64 + c0 * 8];
      bf16x8 k1 = *(const bf16x8*)&Kb[row * 64 + (c0 ^ 4) * 8];
      f32x4 s = {};
      s = __builtin_amdgcn_mfma_f32_16x16x32_bf16(aq0, k0, s, 0, 0, 0);
      s = __builtin_amdgcn_mfma_f32_16x16x32_bf16(aq1, k1, s, 0, 0, 0);
      st[t] = s;
    }
    if (jg == qg) {
      #pragma unroll
      for (int t = 0; t < 4; ++t)
        #pragma unroll
        for (int r = 0; r < 4; ++r)
          st[t][r] = (16 * t + lr > wid * 16 + 4 * lg + r) ? -1e30f : st[t][r];
    }
    #pragma unroll
    for (int r = 0; r < 4; ++r) {
      float p0 = __builtin_exp2f(st[0][r]);
      float p1 = __builtin_exp2f(st[1][r]);
      float p2 = __builtin_exp2f(st[2][r]);
      float p3 = __builtin_exp2f(st[3][r]);
      lsum[r] += (p0 + p1) + (p2 + p3);
      *(unsigned*)&P[4 * lg + r][2 * lr] = cvt_pk_bf16(p0, p1);
      *(unsigned*)&P[4 * lg + r][32 + 2 * lr] = cvt_pk_bf16(p2, p3);
    }
    asm volatile("s_waitcnt lgkmcnt(0)" ::: "memory");  // wave-private P roundtrip
    __builtin_amdgcn_sched_barrier(0);
    bf16x8 pa0 = *(const bf16x8*)&P[lr][8 * lg];
    bf16x8 pa1 = *(const bf16x8*)&P[lr][32 + 8 * lg];
    // V ready: with K(j+1) in flight, vmcnt(2) waits exactly the 2 V loads
    if (j + 1 < nt) asm volatile("s_waitcnt vmcnt(2)" ::: "memory");
    else            asm volatile("s_waitcnt vmcnt(0)" ::: "memory");
    __builtin_amdgcn_sched_barrier(0);
    #pragma unroll
    for (int nv = 0; nv < 4; ++nv) {
      int row0 = nv * 16 + lr;
      int c0 = lg ^ (row0 & 7);
      bf16x8 v0 = *(const bf16x8*)&Vs[row0 * 64 + c0 * 8];
      bf16x8 v1e = *(const bf16x8*)&Vs[row0 * 64 + (c0 ^ 4) * 8];
      accO[nv] = __builtin_amdgcn_mfma_f32_16x16x32_bf16(pa0, v0, accO[nv], 0, 0, 0);
      accO[nv] = __builtin_amdgcn_mfma_f32_16x16x32_bf16(pa1, v1e, accO[nv], 0, 0, 0);
    }
  }

  if (qg < 8) {  // ns==1: this block is the only contributor -> write obT directly
    #pragma unroll
    for (int r = 0; r < 4; ++r) {
      float sres = lsum[r];
      sres += __shfl_xor(sres, 1);
      sres += __shfl_xor(sres, 2);
      sres += __shfl_xor(sres, 4);
      sres += __shfl_xor(sres, 8);
      const int t = qt0 + 4 * lg + r;
      const float gs = gate[t * 16 + head] / sres;
      #pragma unroll
      for (int nv = 0; nv < 4; ++nv) {
        const int col = nv * 16 + lr;
        obT[((size_t)(head * 8 + (col >> 3)) * T_SEQ + t) * 8 + (col & 7)] =
            f2bs(accO[nv][r] * gs);
      }
    }
    return;
  }
  short* pO = partO + (size_t)(head * 80 + b) * 4096;
  float* pL = partL + (size_t)(head * 80 + b) * 64;
  #pragma unroll
  for (int r = 0; r < 4; ++r) {
    float sres = lsum[r];
    sres += __shfl_xor(sres, 1);
    sres += __shfl_xor(sres, 2);
    sres += __shfl_xor(sres, 4);
    sres += __shfl_xor(sres, 8);
    int row = wid * 16 + 4 * lg + r;
    #pragma unroll
    for (int nv = 0; nv < 4; ++nv)
      pO[row * 64 + nv * 16 + lr] = f2bs(accO[nv][r]);
    if (lr == 0) pL[row] = sres;
  }
}

// ------- combine split-KV partials (qg>=8 only), apply gate, write chunk-major obT
__global__ __launch_bounds__(256) void attn_reduce(const short* __restrict__ partO,
                                                   const float* __restrict__ partL,
                                                   const float* __restrict__ gate,
                                                   short* __restrict__ obT) {
  const int head = blockIdx.x & 15;
  const int qg = 8 + (blockIdx.x >> 4);  // 8..31
  const int ns = (qg >> 3) + 1;
  const int tid = threadIdx.x;
  const int row = tid >> 2, q4 = tid & 3;
  const int sbase[4] = {0, 32, 56, 72};  // strip -> b base (b = sbase[s] + 31 - qg)
  f32x4 o[4] = {};
  float l = 0.f;
  for (int s = 0; s < ns; ++s) {
    const int slot = head * 80 + sbase[s] + 31 - qg;
    const short* pb = partO + (size_t)slot * 4096;
    #pragma unroll
    for (int c = 0; c < 4; ++c) {
      bf16x4 v = *(const bf16x4*)&pb[row * 64 + q4 * 16 + c * 4];
      #pragma unroll
      for (int j = 0; j < 4; ++j) o[c][j] += bs2f(v[j]);
    }
    l += partL[(size_t)slot * 64 + row];
  }
  const int t = qg * 64 + row;
  const float gs = gate[t * 16 + head] / l;
  const int cg0 = head * 8 + q4 * 2;
  bf16x8 w0, w1;
  #pragma unroll
  for (int j = 0; j < 4; ++j) {
    w0[j]     = f2bs(o[0][j] * gs);
    w0[4 + j] = f2bs(o[1][j] * gs);
    w1[j]     = f2bs(o[2][j] * gs);
    w1[4 + j] = f2bs(o[3][j] * gs);
  }
  *(bf16x8*)&obT[((size_t)cg0 * 2048 + t) * 8] = w0;
  *(bf16x8*)&obT[((size_t)(cg0 + 1) * 2048 + t) * 8] = w1;
}

extern "C" void kernel_launch(void* const* d_in, const int* in_sizes, int n_in,
                              void* d_out, int out_size, void* d_ws, size_t ws_size,
                              hipStream_t stream) {
  const float* x     = (const float*)d_in[0];
  const float* v1    = (const float*)d_in[1];
  const float* Wq    = (const float*)d_in[2];
  const float* Wk    = (const float*)d_in[3];
  const float* Wv    = (const float*)d_in[4];
  const float* Wproj = (const float*)d_in[5];
  const float* lamb  = (const float*)d_in[6];
  const float* Wgate = (const float*)d_in[7];
  float* out = (float*)d_out;

  char* ws = (char*)d_ws;
  short*  xbT   = (short*)(ws);                       // 4MB chunk-major x (alias obT)
  short*  wqkvT = (short*)(ws + ((size_t)4  << 20));  // 6MB chunk-major Wq|Wk|Wv
  short*  wpjT  = (short*)(ws + ((size_t)10 << 20));  // 2MB chunk-major Wproj
  short*  partO = (short*)(ws + ((size_t)12 << 20));  // 10.5MB bf16 O partials
  float*  partL = (float*)(ws + ((size_t)23 << 20));  // 327KB f32 lsum partials
  float2* rope  = (float2*)(ws + ((size_t)34 << 20)); // 512KB
  short*  qb    = (short*)(ws + ((size_t)36 << 20));  // 4MB
  short*  kb    = (short*)(ws + ((size_t)40 << 20));  // 4MB
  short*  vt    = (short*)(ws + ((size_t)44 << 20));  // 4MB
  float*  gate  = (float*)(ws + ((size_t)48 << 20));  // 128KB
  short*  obT   = xbT;  // xbT dead after QKV GEMM

  prep<<<dim3(96, 9), 256, 0, stream>>>(x, Wq, Wk, Wv, Wproj, Wgate,
                                        xbT, wqkvT, wpjT, gate, rope);
  // QKV: 768 blocks = exactly 3/CU uniform (36KB LDS), XCD-chunked (96 tiles/XCD)
  gemm<64, 128, true><<<768, 256, 0, stream>>>(xbT, wqkvT, nullptr, qb, kb, vt,
                                               v1, lamb, rope, 2048, 3072, 1024, 768);
  attn<<<1280, 256, 0, stream>>>(qb, kb, vt, partO, partL, gate, obT);
  attn_reduce<<<384, 256, 0, stream>>>(partO, partL, gate, obT);
  // proj: 512 GEMM blocks (2/CU uniform, XCD-chunked) + 256 v1-copy tail blocks
  gemm<64, 64, false><<<768, 256, 0, stream>>>(obT, wpjT, out, nullptr, nullptr,
                                               nullptr, v1, nullptr, nullptr,
                                               2048, 1024, 1024, 512);
}